// Round 1
// baseline (659.303 us; speedup 1.0000x reference)
//
#include <hip/hip_runtime.h>
#include <math.h>

#define DD 1024   // hidden dim
#define HH 1408   // moe inter dim
#define NE 8      // experts

typedef __attribute__((ext_vector_type(8))) __bf16 bf16x8;
typedef __attribute__((ext_vector_type(4))) float f32x4;

__device__ __forceinline__ float bf2f(unsigned short u) {
  union { unsigned int i; float f; } v; v.i = ((unsigned int)u) << 16; return v.f;
}
__device__ __forceinline__ unsigned short f2bf(float f) {
  union { float f; unsigned int i; } v; v.f = f;
  unsigned int r = v.i + 0x7FFFu + ((v.i >> 16) & 1u);  // RNE
  return (unsigned short)(r >> 16);
}
__device__ __forceinline__ float tof(float f) { return f; }
__device__ __forceinline__ float tof(unsigned short u) { return bf2f(u); }

// pack bf16(a) | bf16(b)<<16 in ONE instruction (RNE, gfx950)
__device__ __forceinline__ void cvt2(float a, float b, unsigned int* o) {
  asm("v_cvt_pk_bf16_f32 %0, %1, %2" : "=v"(*o) : "v"(a), "v"(b));
}

// ---- 8 contiguous elems -> 4 u32 of packed bf16 pairs ----
__device__ __forceinline__ void ld8cvt(const float* p, unsigned int* o) {
  float4 a = *(const float4*)p;
  float4 b = *(const float4*)(p + 4);
  cvt2(a.x, a.y, o + 0); cvt2(a.z, a.w, o + 1);
  cvt2(b.x, b.y, o + 2); cvt2(b.z, b.w, o + 3);
}
__device__ __forceinline__ void ld8cvt(const unsigned short* p, unsigned int* o) {
  *(uint4*)o = *(const uint4*)p;
}

// ---- two consecutive K-rows x 8 cols -> 8 u32, o[i] = (row0[i], row1[i]) ----
__device__ __forceinline__ void ld2x8pk(const float* p0, const float* p1,
                                        unsigned int* o) {
  float4 a0 = *(const float4*)p0, b0 = *(const float4*)(p0 + 4);
  float4 a1 = *(const float4*)p1, b1 = *(const float4*)(p1 + 4);
  cvt2(a0.x, a1.x, o + 0); cvt2(a0.y, a1.y, o + 1);
  cvt2(a0.z, a1.z, o + 2); cvt2(a0.w, a1.w, o + 3);
  cvt2(b0.x, b1.x, o + 4); cvt2(b0.y, b1.y, o + 5);
  cvt2(b0.z, b1.z, o + 6); cvt2(b0.w, b1.w, o + 7);
}
__device__ __forceinline__ void ld2x8pk(const unsigned short* p0,
                                        const unsigned short* p1,
                                        unsigned int* o) {
  uint4 u0 = *(const uint4*)p0, u1 = *(const uint4*)p1;
  const unsigned int* a = (const unsigned int*)&u0;
  const unsigned int* b = (const unsigned int*)&u1;
#pragma unroll
  for (int w = 0; w < 4; w++) {
    o[2 * w]     = (a[w] & 0xFFFFu) | (b[w] << 16);
    o[2 * w + 1] = (a[w] >> 16) | (b[w] & 0xFFFF0000u);
  }
}

// ---------------- sniff input dtype: 1 = fp32, 0 = bf16 ----------------
__global__ void sniff_kernel(const unsigned short* __restrict__ xw,
                             int* __restrict__ dflag) {
  __shared__ int cnt;
  if (threadIdx.x == 0) cnt = 0;
  __syncthreads();
  unsigned short v = xw[threadIdx.x];
  int e = (v >> 7) & 0xFF;
  if (e >= 100 && e <= 140) atomicAdd(&cnt, 1);
  __syncthreads();
  if (threadIdx.x == 0) dflag[0] = (cnt < 230) ? 1 : 0;
}

// ---------------- gate: one wave per token (full T, once) ----------------
template <class T>
__device__ void gate_body(const T* __restrict__ x,
                          const T* __restrict__ gw,
                          const T* __restrict__ gb,
                          int* __restrict__ tok_eidx,
                          float* __restrict__ tok_w, int T_) {
  int t = (int)((blockIdx.x * blockDim.x + threadIdx.x) >> 6);
  int lane = threadIdx.x & 63;
  if (t >= T_) return;
  const T* xr = x + (size_t)t * DD;
  float acc[NE];
#pragma unroll
  for (int e = 0; e < NE; e++) acc[e] = 0.f;
  for (int i = lane; i < DD; i += 64) {
    float xv = tof(xr[i]);
#pragma unroll
    for (int e = 0; e < NE; e++) acc[e] += xv * tof(gw[e * DD + i]);
  }
#pragma unroll
  for (int off = 32; off > 0; off >>= 1) {
#pragma unroll
    for (int e = 0; e < NE; e++) acc[e] += __shfl_xor(acc[e], off);
  }
  if (lane == 0) {
    float mx = acc[0];
#pragma unroll
    for (int e = 1; e < NE; e++) mx = fmaxf(mx, acc[e]);
    float s = 0.f, sc[NE], bi[NE];
#pragma unroll
    for (int e = 0; e < NE; e++) { sc[e] = expf(acc[e] - mx); s += sc[e]; }
    float inv = 1.f / s;
#pragma unroll
    for (int e = 0; e < NE; e++) { sc[e] *= inv; bi[e] = sc[e] + tof(gb[e]); }
    int i1 = 0;
#pragma unroll
    for (int e = 1; e < NE; e++) if (bi[e] > bi[i1]) i1 = e;
    int i2 = (i1 == 0) ? 1 : 0;
#pragma unroll
    for (int e = 0; e < NE; e++) if (e != i1 && bi[e] > bi[i2]) i2 = e;
    tok_eidx[t * 2] = i1; tok_eidx[t * 2 + 1] = i2;
    tok_w[t * 2] = sc[i1]; tok_w[t * 2 + 1] = sc[i2];
  }
}

__global__ void gate_kernel(const void* x, const void* gw, const void* gb,
                            const int* __restrict__ dflag,
                            int* tok_eidx, float* tok_w, int T_) {
  if (dflag[0])
    gate_body<float>((const float*)x, (const float*)gw, (const float*)gb,
                     tok_eidx, tok_w, T_);
  else
    gate_body<unsigned short>((const unsigned short*)x, (const unsigned short*)gw,
                              (const unsigned short*)gb, tok_eidx, tok_w, T_);
}

// ---------------- fused count + scan + scatter (single block) ----------------
__global__ void prep_kernel(const int* __restrict__ tok_eidx,
                            const float* __restrict__ tok_w,
                            int* __restrict__ meta,
                            int* __restrict__ rows_tok,
                            float* __restrict__ rows_wgt,
                            int t0, int TS) {
  __shared__ int cnt[NE];
  __shared__ int off[NE];
  const int tid = threadIdx.x;
  if (tid < NE) cnt[tid] = 0;
  __syncthreads();
  const int n2 = TS * 2;
  const int* te = tok_eidx + (size_t)t0 * 2;
  const float* tw = tok_w + (size_t)t0 * 2;
  for (int i = tid; i < n2; i += (int)blockDim.x) atomicAdd(&cnt[te[i]], 1);
  __syncthreads();
  if (tid == 0) {
    int s = 0;
#pragma unroll
    for (int e = 0; e < NE; e++) { off[e] = s; meta[16 + e] = s; s += cnt[e]; }
    meta[16 + NE] = s;
  }
  __syncthreads();
  for (int i = tid; i < n2; i += (int)blockDim.x) {
    int pos = atomicAdd(&off[te[i]], 1);
    rows_tok[pos] = t0 + (i >> 1);
    rows_wgt[pos] = tw[i];
  }
}

// ---------------- zero fp32 output ----------------
__global__ void zero_kernel(float4* __restrict__ p, int n4) {
  int i = blockIdx.x * blockDim.x + threadIdx.x;
  int st = gridDim.x * blockDim.x;
  float4 z; z.x = z.y = z.z = z.w = 0.f;
  for (; i < n4; i += st) p[i] = z;
}

// ---------------- up-projection (128x128 tile, 64-K per barrier pair) ----------------
template <class T>
__device__ void up_body(const T* __restrict__ x,
                        const T* __restrict__ w1, const T* __restrict__ w3,
                        const T* __restrict__ b1, const T* __restrict__ b3,
                        const T* __restrict__ sw1, const T* __restrict__ sw3,
                        const T* __restrict__ sb1, const T* __restrict__ sb3,
                        const int* __restrict__ meta,
                        const int* __restrict__ rows_tok,
                        unsigned short* __restrict__ h_buf,
                        unsigned short* __restrict__ sh_buf,
                        int t0, int TS) {
  const int z = blockIdx.z;
  const bool sh = (z == NE);
  int g0, cnt;
  const T *wa, *wb, *ba, *bb;
  unsigned short* ho;
  if (sh) {
    g0 = 0; cnt = TS; wa = sw1; wb = sw3; ba = sb1; bb = sb3; ho = sh_buf;
  } else {
    g0 = meta[16 + z]; cnt = meta[17 + z] - g0;
    wa = w1 + (size_t)z * DD * HH; wb = w3 + (size_t)z * DD * HH;
    ba = b1 + (size_t)z * HH;      bb = b3 + (size_t)z * HH;
    ho = h_buf + (size_t)g0 * HH;
  }
  const int mtile = blockIdx.y;
  if (mtile * 128 >= cnt) return;
  const int n0 = blockIdx.x * 128;

  __shared__ alignas(16) unsigned short lds_a[2][128 * 40];
  __shared__ alignas(16) unsigned short lds_b1[2][128 * 40];
  __shared__ alignas(16) unsigned short lds_b3[2][128 * 40];

  const int tid = threadIdx.x;

  // A staging: idx = p*256+tid covers 128 rows x 4 chunks-of-8 (32 K)
  size_t abase[2];
  int aoff[2];
#pragma unroll
  for (int p = 0; p < 2; p++) {
    int idx = p * 256 + tid;
    int row = idx >> 2, c = (idx & 3) << 3;
    int m = mtile * 128 + row;
    int srow;
    if (sh) srow = t0 + ((m < cnt) ? m : (cnt - 1));
    else { int r = (m < cnt) ? m : (cnt - 1); srow = rows_tok[g0 + r]; }
    abase[p] = (size_t)srow * DD + c;
    aoff[p] = row * 40 + c;
  }
  // B staging: kk pair from LOW tid bits, n-group from HIGH bits
  // (compile-time pk indices; avoids runtime-indexed local arrays)
  const int kk2 = (tid & 15) << 1;     // 0..30
  const int n8 = (tid >> 4) << 3;      // 0..120
  int boffc[8];
#pragma unroll
  for (int i = 0; i < 8; i++) boffc[i] = (n8 + i) * 40 + kk2;
  const size_t bcol = (size_t)(n0 + n8);

  const int wid = tid >> 6;
  const int wrow = (wid >> 1) << 6, wcol = (wid & 1) << 6;
  const int ln15 = tid & 15;
  const int kq8 = ((tid & 63) >> 4) << 3;

  f32x4 acc1[4][4], acc3[4][4];
#pragma unroll
  for (int a = 0; a < 4; a++)
#pragma unroll
    for (int b = 0; b < 4; b++) {
      acc1[a][b] = {0.f, 0.f, 0.f, 0.f};
      acc3[a][b] = {0.f, 0.f, 0.f, 0.f};
    }

  for (int k0 = 0; k0 < DD; k0 += 64) {
    __syncthreads();
#pragma unroll
    for (int hB = 0; hB < 2; hB++) {
      const int kb = k0 + hB * 32;
#pragma unroll
      for (int p = 0; p < 2; p++) {
        unsigned int tmp[4];
        ld8cvt(x + abase[p] + kb, tmp);
        *(uint4*)&lds_a[hB][aoff[p]] = *(uint4*)tmp;
      }
      unsigned int pk[8];
      ld2x8pk(wa + (size_t)(kb + kk2) * HH + bcol,
              wa + (size_t)(kb + kk2 + 1) * HH + bcol, pk);
#pragma unroll
      for (int i = 0; i < 8; i++)
        *(unsigned int*)&lds_b1[hB][boffc[i]] = pk[i];
      ld2x8pk(wb + (size_t)(kb + kk2) * HH + bcol,
              wb + (size_t)(kb + kk2 + 1) * HH + bcol, pk);
#pragma unroll
      for (int i = 0; i < 8; i++)
        *(unsigned int*)&lds_b3[hB][boffc[i]] = pk[i];
    }
    __syncthreads();
#pragma unroll
    for (int hB = 0; hB < 2; hB++) {
      bf16x8 af[4];
#pragma unroll
      for (int fm = 0; fm < 4; fm++)
        af[fm] = *(const bf16x8*)&lds_a[hB][(wrow + fm * 16 + ln15) * 40 + kq8];
#pragma unroll
      for (int fn = 0; fn < 4; fn++) {
        bf16x8 bv1 = *(const bf16x8*)&lds_b1[hB][(wcol + fn * 16 + ln15) * 40 + kq8];
        bf16x8 bv3 = *(const bf16x8*)&lds_b3[hB][(wcol + fn * 16 + ln15) * 40 + kq8];
#pragma unroll
        for (int fm = 0; fm < 4; fm++) {
          acc1[fm][fn] = __builtin_amdgcn_mfma_f32_16x16x32_bf16(af[fm], bv1, acc1[fm][fn], 0, 0, 0);
          acc3[fm][fn] = __builtin_amdgcn_mfma_f32_16x16x32_bf16(af[fm], bv3, acc3[fm][fn], 0, 0, 0);
        }
      }
    }
  }

  const int kq4 = ((tid & 63) >> 4) << 2;
#pragma unroll
  for (int fm = 0; fm < 4; fm++) {
#pragma unroll
    for (int r = 0; r < 4; r++) {
      int m = mtile * 128 + wrow + fm * 16 + kq4 + r;
      if (m < cnt) {
        unsigned short* orow = ho + (size_t)m * HH + n0;
#pragma unroll
        for (int fn = 0; fn < 4; fn++) {
          int nc = wcol + fn * 16 + ln15;
          float g1 = acc1[fm][fn][r] + tof(ba[n0 + nc]);
          float g3 = acc3[fm][fn][r] + tof(bb[n0 + nc]);
          float u = g1 * g3;
          float hv = u * __builtin_amdgcn_rcpf(1.f + __expf(-u));  // silu(g1*g3)
          orow[nc] = f2bf(hv);
        }
      }
    }
  }
}

__global__ __launch_bounds__(256, 2)
void ffn_up_kernel(const void* x, const void* w1, const void* w3,
                   const void* b1, const void* b3,
                   const void* sw1, const void* sw3,
                   const void* sb1, const void* sb3,
                   const int* __restrict__ dflag,
                   const int* meta, const int* rows_tok,
                   unsigned short* h_buf, unsigned short* sh_buf,
                   int t0, int TS) {
  if (dflag[0])
    up_body<float>((const float*)x, (const float*)w1, (const float*)w3,
                   (const float*)b1, (const float*)b3, (const float*)sw1,
                   (const float*)sw3, (const float*)sb1, (const float*)sb3,
                   meta, rows_tok, h_buf, sh_buf, t0, TS);
  else
    up_body<unsigned short>((const unsigned short*)x, (const unsigned short*)w1,
                            (const unsigned short*)w3, (const unsigned short*)b1,
                            (const unsigned short*)b3, (const unsigned short*)sw1,
                            (const unsigned short*)sw3, (const unsigned short*)sb1,
                            (const unsigned short*)sb3,
                            meta, rows_tok, h_buf, sh_buf, t0, TS);
}

// ---------------- down-projection (accumulates straight into d_out) ----------------
template <class T>
__device__ void down_body(const unsigned short* __restrict__ h_buf,
                          const unsigned short* __restrict__ sh_buf,
                          const T* __restrict__ w2, const T* __restrict__ b2,
                          const T* __restrict__ sw2, const T* __restrict__ sb2,
                          const int* __restrict__ meta,
                          const int* __restrict__ rows_tok,
                          const float* __restrict__ rows_wgt,
                          float* __restrict__ out,
                          int t0, int TS) {
  const int z = blockIdx.z;
  const bool sh = (z == NE);
  int g0, cnt;
  const T *wsrc, *bsrc;
  const unsigned short* hb;
  if (sh) { g0 = 0; cnt = TS; wsrc = sw2; bsrc = sb2; hb = sh_buf; }
  else {
    g0 = meta[16 + z]; cnt = meta[17 + z] - g0;
    wsrc = w2 + (size_t)z * HH * DD; bsrc = b2 + (size_t)z * DD;
    hb = h_buf + (size_t)g0 * HH;
  }
  const int mtile = blockIdx.y;
  if (mtile * 128 >= cnt) return;
  const int n0 = blockIdx.x * 128;

  __shared__ alignas(16) unsigned short lds_a[2][128 * 40];
  __shared__ alignas(16) unsigned short lds_b[2][128 * 40];

  const int tid = threadIdx.x;
  const unsigned short* asrc[2];
  int aoff[2];
#pragma unroll
  for (int p = 0; p < 2; p++) {
    int idx = p * 256 + tid;
    int row = idx >> 2, c = (idx & 3) << 3;
    int m = mtile * 128 + row;
    int r = (m < cnt) ? m : (cnt - 1);
    asrc[p] = hb + (size_t)r * HH + c;
    aoff[p] = row * 40 + c;
  }
  const int kk2 = (tid & 15) << 1;
  const int n8 = (tid >> 4) << 3;
  int boffc[8];
#pragma unroll
  for (int i = 0; i < 8; i++) boffc[i] = (n8 + i) * 40 + kk2;
  const size_t bcol = (size_t)(n0 + n8);

  const int wid = tid >> 6;
  const int wrow = (wid >> 1) << 6, wcol = (wid & 1) << 6;
  const int ln15 = tid & 15;
  const int kq8 = ((tid & 63) >> 4) << 3;

  f32x4 acc[4][4];
#pragma unroll
  for (int a = 0; a < 4; a++)
#pragma unroll
    for (int b = 0; b < 4; b++) acc[a][b] = {0.f, 0.f, 0.f, 0.f};

  for (int k0 = 0; k0 < HH; k0 += 64) {
    __syncthreads();
#pragma unroll
    for (int hB = 0; hB < 2; hB++) {
      const int kb = k0 + hB * 32;
#pragma unroll
      for (int p = 0; p < 2; p++)
        *(uint4*)&lds_a[hB][aoff[p]] = *(const uint4*)(asrc[p] + kb);
      unsigned int pk[8];
      ld2x8pk(wsrc + (size_t)(kb + kk2) * DD + bcol,
              wsrc + (size_t)(kb + kk2 + 1) * DD + bcol, pk);
#pragma unroll
      for (int i = 0; i < 8; i++)
        *(unsigned int*)&lds_b[hB][boffc[i]] = pk[i];
    }
    __syncthreads();
#pragma unroll
    for (int hB = 0; hB < 2; hB++) {
      bf16x8 af[4];
#pragma unroll
      for (int fm = 0; fm < 4; fm++)
        af[fm] = *(const bf16x8*)&lds_a[hB][(wrow + fm * 16 + ln15) * 40 + kq8];
#pragma unroll
      for (int fn = 0; fn < 4; fn++) {
        bf16x8 bv = *(const bf16x8*)&lds_b[hB][(wcol + fn * 16 + ln15) * 40 + kq8];
#pragma unroll
        for (int fm = 0; fm < 4; fm++)
          acc[fm][fn] = __builtin_amdgcn_mfma_f32_16x16x32_bf16(af[fm], bv, acc[fm][fn], 0, 0, 0);
      }
    }
  }

  const int kq4 = ((tid & 63) >> 4) << 2;
#pragma unroll
  for (int fm = 0; fm < 4; fm++) {
#pragma unroll
    for (int r = 0; r < 4; r++) {
      int m = mtile * 128 + wrow + fm * 16 + kq4 + r;
      if (m < cnt) {
        int t; float wgt;
        if (sh) { t = t0 + m; wgt = 1.f; }
        else { t = rows_tok[g0 + m]; wgt = rows_wgt[g0 + m]; }
        float* orow = out + (size_t)t * DD + n0;
#pragma unroll
        for (int fn = 0; fn < 4; fn++) {
          int nc = wcol + fn * 16 + ln15;
          float v = wgt * (acc[fm][fn][r] + tof(bsrc[n0 + nc]));
          atomicAdd(&orow[nc], v);
        }
      }
    }
  }
}

__global__ __launch_bounds__(256, 2)
void ffn_down_kernel(const unsigned short* h_buf, const unsigned short* sh_buf,
                     const void* w2, const void* b2,
                     const void* sw2, const void* sb2,
                     const int* __restrict__ dflag,
                     const int* meta, const int* rows_tok, const float* rows_wgt,
                     float* out, int t0, int TS) {
  if (dflag[0])
    down_body<float>(h_buf, sh_buf, (const float*)w2, (const float*)b2,
                     (const float*)sw2, (const float*)sb2,
                     meta, rows_tok, rows_wgt, out, t0, TS);
  else
    down_body<unsigned short>(h_buf, sh_buf, (const unsigned short*)w2,
                              (const unsigned short*)b2, (const unsigned short*)sw2,
                              (const unsigned short*)sb2,
                              meta, rows_tok, rows_wgt, out, t0, TS);
}

extern "C" void kernel_launch(void* const* d_in, const int* in_sizes, int n_in,
                              void* d_out, int out_size, void* d_ws, size_t ws_size,
                              hipStream_t stream) {
  const void* x   = d_in[0];
  const void* gw  = d_in[1];
  const void* gb  = d_in[2];
  const void* w1  = d_in[3];
  const void* b1  = d_in[4];
  const void* w3  = d_in[5];
  const void* b3  = d_in[6];
  const void* w2  = d_in[7];
  const void* b2  = d_in[8];
  const void* sw1 = d_in[9];
  const void* sb1 = d_in[10];
  const void* sw3 = d_in[11];
  const void* sb3 = d_in[12];
  const void* sw2 = d_in[13];
  const void* sb2 = d_in[14];

  const int T = in_sizes[0] / DD;  // 4096
  (void)n_in; (void)out_size;

  auto need = [&](int S) -> size_t {
    int TS = T / S;
    size_t o = 0;
    auto pad = [&](size_t b) { o = (o + b + 255) & ~(size_t)255; };
    pad(256);                                 // dflag
    pad(32 * sizeof(int));                    // meta
    pad((size_t)T * 2 * sizeof(int));         // tok_eidx
    pad((size_t)T * 2 * sizeof(float));       // tok_w
    pad((size_t)TS * 2 * sizeof(int));        // rows_tok
    pad((size_t)TS * 2 * sizeof(float));      // rows_wgt
    pad((size_t)TS * 2 * HH * 2);             // h_buf
    pad((size_t)TS * HH * 2);                 // sh_buf
    return o;
  };
  int S = 32;
  {
    const int cand[6] = {1, 2, 4, 8, 16, 32};
    for (int ci = 0; ci < 6; ci++) {
      if (need(cand[ci]) <= ws_size) { S = cand[ci]; break; }
    }
  }
  const int TS = T / S;
  const int mt = TS / 128;

  char* w = (char*)d_ws;
  size_t off = 0;
  auto take = [&](size_t bytes) {
    char* p = w + off;
    off = (off + bytes + 255) & ~(size_t)255;
    return p;
  };
  int*   dflag    = (int*)  take(256);
  int*   meta     = (int*)  take(32 * sizeof(int));
  int*   tok_eidx = (int*)  take((size_t)T * 2 * sizeof(int));
  float* tok_w    = (float*)take((size_t)T * 2 * sizeof(float));
  int*   rows_tok = (int*)  take((size_t)TS * 2 * sizeof(int));
  float* rows_wgt = (float*)take((size_t)TS * 2 * sizeof(float));
  unsigned short* h_buf  = (unsigned short*)take((size_t)TS * 2 * HH * 2);
  unsigned short* sh_buf = (unsigned short*)take((size_t)TS * HH * 2);

  sniff_kernel<<<1, 256, 0, stream>>>((const unsigned short*)x, dflag);
  gate_kernel<<<(T + 3) / 4, 256, 0, stream>>>(x, gw, gb, dflag, tok_eidx, tok_w, T);
  zero_kernel<<<2048, 256, 0, stream>>>((float4*)d_out, T * DD / 4);

  for (int s = 0; s < S; s++) {
    const int t0 = s * TS;
    prep_kernel<<<1, 1024, 0, stream>>>(tok_eidx, tok_w, meta, rows_tok, rows_wgt, t0, TS);
    ffn_up_kernel<<<dim3(HH / 128, mt, NE + 1), 256, 0, stream>>>(
        x, w1, w3, b1, b3, sw1, sw3, sb1, sb3, dflag, meta, rows_tok, h_buf, sh_buf, t0, TS);
    ffn_down_kernel<<<dim3(DD / 128, mt, NE + 1), 256, 0, stream>>>(
        h_buf, sh_buf, w2, b2, sw2, sb2, dflag, meta, rows_tok, rows_wgt,
        (float*)d_out, t0, TS);
  }
}

// Round 2
// 502.404 us; speedup vs baseline: 1.3123x; 1.3123x over previous
//
#include <hip/hip_runtime.h>
#include <math.h>

#define DD 1024   // hidden dim
#define HH 1408   // moe inter dim
#define NE 8      // experts

typedef __attribute__((ext_vector_type(8))) __bf16 bf16x8;
typedef __attribute__((ext_vector_type(4))) float f32x4;

__device__ __forceinline__ float bf2f(unsigned short u) {
  union { unsigned int i; float f; } v; v.i = ((unsigned int)u) << 16; return v.f;
}
__device__ __forceinline__ unsigned short f2bf(float f) {
  union { float f; unsigned int i; } v; v.f = f;
  unsigned int r = v.i + 0x7FFFu + ((v.i >> 16) & 1u);  // RNE
  return (unsigned short)(r >> 16);
}
__device__ __forceinline__ float tof(float f) { return f; }
__device__ __forceinline__ float tof(unsigned short u) { return bf2f(u); }

// pack bf16(a) | bf16(b)<<16 in ONE instruction (RNE, gfx950)
__device__ __forceinline__ void cvt2(float a, float b, unsigned int* o) {
  asm("v_cvt_pk_bf16_f32 %0, %1, %2" : "=v"(*o) : "v"(a), "v"(b));
}

__device__ __forceinline__ void ld8cvt(const float* p, unsigned int* o) {
  float4 a = *(const float4*)p;
  float4 b = *(const float4*)(p + 4);
  cvt2(a.x, a.y, o + 0); cvt2(a.z, a.w, o + 1);
  cvt2(b.x, b.y, o + 2); cvt2(b.z, b.w, o + 3);
}

// ---------------- sniff input dtype: 1 = fp32, 0 = bf16 ----------------
__global__ void sniff_kernel(const unsigned short* __restrict__ xw,
                             int* __restrict__ dflag) {
  __shared__ int cnt;
  if (threadIdx.x == 0) cnt = 0;
  __syncthreads();
  unsigned short v = xw[threadIdx.x];
  int e = (v >> 7) & 0xFF;
  if (e >= 100 && e <= 140) atomicAdd(&cnt, 1);
  __syncthreads();
  if (threadIdx.x == 0) dflag[0] = (cnt < 230) ? 1 : 0;
}

// ---------------- convert x -> bf16 ----------------
__global__ void cvtx_kernel(const void* __restrict__ x,
                            const int* __restrict__ dflag,
                            unsigned short* __restrict__ xb, int n8) {
  int i = blockIdx.x * blockDim.x + threadIdx.x;
  int st = gridDim.x * blockDim.x;
  if (dflag[0]) {
    const float* xs = (const float*)x;
    for (; i < n8; i += st) {
      unsigned int o[4];
      ld8cvt(xs + (size_t)i * 8, o);
      *(uint4*)(xb + (size_t)i * 8) = *(uint4*)o;
    }
  } else {
    const uint4* xs = (const uint4*)x;
    for (; i < n8; i += st) *(uint4*)(xb + (size_t)i * 8) = xs[i];
  }
}

// ---------------- transpose+convert weights: [mat][R][C] -> [mat][C][R] bf16 ----
// mat 0..NE-1 from wmain, mat NE from wsh (shared expert)
__global__ void trans_kernel(const void* __restrict__ wmain,
                             const void* __restrict__ wsh,
                             const int* __restrict__ dflag,
                             unsigned short* __restrict__ out, int R, int C) {
  __shared__ float tile[32][33];
  const int mat = blockIdx.z;
  const int r0 = blockIdx.y << 5, c0 = blockIdx.x << 5;
  const int t = threadIdx.x;                 // 256 threads
  const int lr = t >> 3, lc = (t & 7) << 2;  // each thread: 4 consecutive cols
  const size_t mbase = (size_t)mat * R * C;
  if (dflag[0]) {
    const float* src = (mat < NE) ? ((const float*)wmain + mbase) : (const float*)wsh;
    float4 v = *(const float4*)(src + (size_t)(r0 + lr) * C + c0 + lc);
    tile[lr][lc] = v.x; tile[lr][lc + 1] = v.y;
    tile[lr][lc + 2] = v.z; tile[lr][lc + 3] = v.w;
  } else {
    const unsigned short* src = (mat < NE) ? ((const unsigned short*)wmain + mbase)
                                           : (const unsigned short*)wsh;
    ushort4 v = *(const ushort4*)(src + (size_t)(r0 + lr) * C + c0 + lc);
    tile[lr][lc] = bf2f(v.x); tile[lr][lc + 1] = bf2f(v.y);
    tile[lr][lc + 2] = bf2f(v.z); tile[lr][lc + 3] = bf2f(v.w);
  }
  __syncthreads();
  const int oc = t >> 3;         // output row offset (= tile col)
  const int orr = (t & 7) << 2;  // output col base (= tile row)
  unsigned int p0, p1;
  cvt2(tile[orr][oc], tile[orr + 1][oc], &p0);
  cvt2(tile[orr + 2][oc], tile[orr + 3][oc], &p1);
  uint2 pk; pk.x = p0; pk.y = p1;
  *(uint2*)(out + mbase + (size_t)(c0 + oc) * R + r0 + orr) = pk;
}

// ---------------- biases -> f32, [NE+1] stacked (slot NE = shared) ----------
__global__ void cvtb_kernel(const void* b1, const void* b3, const void* b2,
                            const void* sb1, const void* sb3, const void* sb2,
                            const int* __restrict__ dflag,
                            float* __restrict__ bf1, float* __restrict__ bf3,
                            float* __restrict__ bf2o) {
  int i = blockIdx.x * blockDim.x + threadIdx.x;
  const int nh = (NE + 1) * HH, nd = (NE + 1) * DD;
  const bool f32 = dflag[0] != 0;
  auto get = [&](const void* pm, const void* ps, int idx, int per) -> float {
    int mat = idx / per, j = idx - mat * per;
    if (f32) return (mat < NE) ? ((const float*)pm)[(size_t)mat * per + j]
                               : ((const float*)ps)[j];
    return bf2f((mat < NE) ? ((const unsigned short*)pm)[(size_t)mat * per + j]
                           : ((const unsigned short*)ps)[j]);
  };
  if (i < nh) bf1[i] = get(b1, sb1, i, HH);
  else if (i < 2 * nh) bf3[i - nh] = get(b3, sb3, i - nh, HH);
  else if (i < 2 * nh + nd) bf2o[i - 2 * nh] = get(b2, sb2, i - 2 * nh, DD);
}

// ---------------- gate: one wave per token (reads raw x for precision) -----
template <class T>
__device__ void gate_body(const T* __restrict__ x,
                          const T* __restrict__ gw,
                          const T* __restrict__ gb,
                          int* __restrict__ tok_eidx,
                          float* __restrict__ tok_w, int T_) {
  int t = (int)((blockIdx.x * blockDim.x + threadIdx.x) >> 6);
  int lane = threadIdx.x & 63;
  if (t >= T_) return;
  const T* xr = x + (size_t)t * DD;
  float acc[NE];
#pragma unroll
  for (int e = 0; e < NE; e++) acc[e] = 0.f;
  for (int i = lane; i < DD; i += 64) {
    float xv = tof(xr[i]);
#pragma unroll
    for (int e = 0; e < NE; e++) acc[e] += xv * tof(gw[e * DD + i]);
  }
#pragma unroll
  for (int off = 32; off > 0; off >>= 1) {
#pragma unroll
    for (int e = 0; e < NE; e++) acc[e] += __shfl_xor(acc[e], off);
  }
  if (lane == 0) {
    float mx = acc[0];
#pragma unroll
    for (int e = 1; e < NE; e++) mx = fmaxf(mx, acc[e]);
    float s = 0.f, sc[NE], bi[NE];
#pragma unroll
    for (int e = 0; e < NE; e++) { sc[e] = expf(acc[e] - mx); s += sc[e]; }
    float inv = 1.f / s;
#pragma unroll
    for (int e = 0; e < NE; e++) { sc[e] *= inv; bi[e] = sc[e] + tof(gb[e]); }
    int i1 = 0;
#pragma unroll
    for (int e = 1; e < NE; e++) if (bi[e] > bi[i1]) i1 = e;
    int i2 = (i1 == 0) ? 1 : 0;
#pragma unroll
    for (int e = 0; e < NE; e++) if (e != i1 && bi[e] > bi[i2]) i2 = e;
    tok_eidx[t * 2] = i1; tok_eidx[t * 2 + 1] = i2;
    tok_w[t * 2] = sc[i1]; tok_w[t * 2 + 1] = sc[i2];
  }
}

__global__ void gate_kernel(const void* x, const void* gw, const void* gb,
                            const int* __restrict__ dflag,
                            int* tok_eidx, float* tok_w, int T_) {
  if (dflag[0])
    gate_body<float>((const float*)x, (const float*)gw, (const float*)gb,
                     tok_eidx, tok_w, T_);
  else
    gate_body<unsigned short>((const unsigned short*)x, (const unsigned short*)gw,
                              (const unsigned short*)gb, tok_eidx, tok_w, T_);
}

// ---------------- fused count + scan + scatter (single block) ----------------
__global__ void prep_kernel(const int* __restrict__ tok_eidx,
                            const float* __restrict__ tok_w,
                            int* __restrict__ meta,
                            int* __restrict__ rows_tok,
                            float* __restrict__ rows_wgt,
                            int t0, int TS) {
  __shared__ int cnt[NE];
  __shared__ int off[NE];
  const int tid = threadIdx.x;
  if (tid < NE) cnt[tid] = 0;
  __syncthreads();
  const int n2 = TS * 2;
  const int* te = tok_eidx + (size_t)t0 * 2;
  const float* tw = tok_w + (size_t)t0 * 2;
  for (int i = tid; i < n2; i += (int)blockDim.x) atomicAdd(&cnt[te[i]], 1);
  __syncthreads();
  if (tid == 0) {
    int s = 0;
#pragma unroll
    for (int e = 0; e < NE; e++) { off[e] = s; meta[16 + e] = s; s += cnt[e]; }
    meta[16 + NE] = s;
  }
  __syncthreads();
  for (int i = tid; i < n2; i += (int)blockDim.x) {
    int pos = atomicAdd(&off[te[i]], 1);
    rows_tok[pos] = t0 + (i >> 1);
    rows_wgt[pos] = tw[i];
  }
}

// ---------------- zero fp32 output ----------------
__global__ void zero_kernel(float4* __restrict__ p, int n4) {
  int i = blockIdx.x * blockDim.x + threadIdx.x;
  int st = gridDim.x * blockDim.x;
  float4 z; z.x = z.y = z.z = z.w = 0.f;
  for (; i < n4; i += st) p[i] = z;
}

// ---------------- up-projection: bf16, 128x128 tile, 8 waves, BK=32 --------
__global__ __launch_bounds__(512, 4)
void ffn_up_kernel(const unsigned short* __restrict__ xb,
                   const unsigned short* __restrict__ wt1,
                   const unsigned short* __restrict__ wt3,
                   const float* __restrict__ bf1, const float* __restrict__ bf3,
                   const int* __restrict__ meta,
                   const int* __restrict__ rows_tok,
                   unsigned short* __restrict__ h_buf,
                   unsigned short* __restrict__ sh_buf,
                   int t0, int TS) {
  const int z = blockIdx.z;
  const bool shx = (z == NE);
  int g0, cnt;
  unsigned short* ho;
  if (shx) { g0 = 0; cnt = TS; ho = sh_buf; }
  else {
    g0 = meta[16 + z]; cnt = meta[17 + z] - g0;
    ho = h_buf + (size_t)g0 * HH;
  }
  const int mtile = blockIdx.y;
  if (mtile * 128 >= cnt) return;
  const int n0 = blockIdx.x * 128;
  const unsigned short* wa = wt1 + (size_t)z * HH * DD;  // [HH][DD] bf16
  const unsigned short* wb = wt3 + (size_t)z * HH * DD;

  __shared__ alignas(16) unsigned short lds_a[128 * 40];
  __shared__ alignas(16) unsigned short lds_b1[128 * 40];
  __shared__ alignas(16) unsigned short lds_b3[128 * 40];

  const int tid = threadIdx.x;
  // staging map: 512 threads cover 128 rows x 4 chunks-of-8 (one 16B granule each)
  const int row = tid >> 2, cc = (tid & 3) << 3;
  int m = mtile * 128 + row;
  int srow;
  if (shx) srow = t0 + ((m < cnt) ? m : (cnt - 1));
  else { int r = (m < cnt) ? m : (cnt - 1); srow = rows_tok[g0 + r]; }
  const size_t abase = (size_t)srow * DD + cc;
  const size_t bbase = (size_t)(n0 + row) * DD + cc;
  const int soff = row * 40 + cc;

  const int wid = tid >> 6;
  const int wrow = (wid >> 1) << 5;  // 0,32,64,96
  const int wcol = (wid & 1) << 6;   // 0,64
  const int ln15 = tid & 15;
  const int kq8 = ((tid & 63) >> 4) << 3;

  f32x4 acc1[2][4], acc3[2][4];
#pragma unroll
  for (int a = 0; a < 2; a++)
#pragma unroll
    for (int b = 0; b < 4; b++) {
      acc1[a][b] = {0.f, 0.f, 0.f, 0.f};
      acc3[a][b] = {0.f, 0.f, 0.f, 0.f};
    }

  for (int k0 = 0; k0 < DD; k0 += 32) {
    __syncthreads();
    *(uint4*)&lds_a[soff]  = *(const uint4*)(xb + abase + k0);
    *(uint4*)&lds_b1[soff] = *(const uint4*)(wa + bbase + k0);
    *(uint4*)&lds_b3[soff] = *(const uint4*)(wb + bbase + k0);
    __syncthreads();
    bf16x8 af[2];
#pragma unroll
    for (int fm = 0; fm < 2; fm++)
      af[fm] = *(const bf16x8*)&lds_a[(wrow + fm * 16 + ln15) * 40 + kq8];
#pragma unroll
    for (int fn = 0; fn < 4; fn++) {
      bf16x8 bv1 = *(const bf16x8*)&lds_b1[(wcol + fn * 16 + ln15) * 40 + kq8];
      bf16x8 bv3 = *(const bf16x8*)&lds_b3[(wcol + fn * 16 + ln15) * 40 + kq8];
#pragma unroll
      for (int fm = 0; fm < 2; fm++) {
        acc1[fm][fn] = __builtin_amdgcn_mfma_f32_16x16x32_bf16(af[fm], bv1, acc1[fm][fn], 0, 0, 0);
        acc3[fm][fn] = __builtin_amdgcn_mfma_f32_16x16x32_bf16(af[fm], bv3, acc3[fm][fn], 0, 0, 0);
      }
    }
  }

  const int kq4 = ((tid & 63) >> 4) << 2;
#pragma unroll
  for (int fm = 0; fm < 2; fm++) {
#pragma unroll
    for (int r = 0; r < 4; r++) {
      int mm = mtile * 128 + wrow + fm * 16 + kq4 + r;
      if (mm < cnt) {
        unsigned short* orow = ho + (size_t)mm * HH + n0;
#pragma unroll
        for (int fn = 0; fn < 4; fn++) {
          int nc = wcol + fn * 16 + ln15;
          float g1 = acc1[fm][fn][r] + bf1[(size_t)z * HH + n0 + nc];
          float g3 = acc3[fm][fn][r] + bf3[(size_t)z * HH + n0 + nc];
          float u = g1 * g3;
          float hv = u * __builtin_amdgcn_rcpf(1.f + __expf(-u));  // silu(g1*g3)
          orow[nc] = f2bf(hv);
        }
      }
    }
  }
}

// ---------------- down-projection: bf16, accumulates into d_out ------------
__global__ __launch_bounds__(512, 4)
void ffn_down_kernel(const unsigned short* __restrict__ h_buf,
                     const unsigned short* __restrict__ sh_buf,
                     const unsigned short* __restrict__ wt2,
                     const float* __restrict__ bf2,
                     const int* __restrict__ meta,
                     const int* __restrict__ rows_tok,
                     const float* __restrict__ rows_wgt,
                     float* __restrict__ out, int t0, int TS) {
  const int z = blockIdx.z;
  const bool shx = (z == NE);
  int g0, cnt;
  const unsigned short* hb;
  if (shx) { g0 = 0; cnt = TS; hb = sh_buf; }
  else {
    g0 = meta[16 + z]; cnt = meta[17 + z] - g0;
    hb = h_buf + (size_t)g0 * HH;
  }
  const int mtile = blockIdx.y;
  if (mtile * 128 >= cnt) return;
  const int n0 = blockIdx.x * 128;
  const unsigned short* wsrc = wt2 + (size_t)z * DD * HH;  // [DD][HH] bf16

  __shared__ alignas(16) unsigned short lds_a[128 * 40];
  __shared__ alignas(16) unsigned short lds_b[128 * 40];

  const int tid = threadIdx.x;
  const int row = tid >> 2, cc = (tid & 3) << 3;
  int m = mtile * 128 + row;
  int r = (m < cnt) ? m : (cnt - 1);
  const unsigned short* asrc = hb + (size_t)r * HH + cc;
  const size_t bbase = (size_t)(n0 + row) * HH + cc;
  const int soff = row * 40 + cc;

  const int wid = tid >> 6;
  const int wrow = (wid >> 1) << 5;
  const int wcol = (wid & 1) << 6;
  const int ln15 = tid & 15;
  const int kq8 = ((tid & 63) >> 4) << 3;

  f32x4 acc[2][4];
#pragma unroll
  for (int a = 0; a < 2; a++)
#pragma unroll
    for (int b = 0; b < 4; b++) acc[a][b] = {0.f, 0.f, 0.f, 0.f};

  for (int k0 = 0; k0 < HH; k0 += 32) {
    __syncthreads();
    *(uint4*)&lds_a[soff] = *(const uint4*)(asrc + k0);
    *(uint4*)&lds_b[soff] = *(const uint4*)(wsrc + bbase + k0);
    __syncthreads();
    bf16x8 af[2];
#pragma unroll
    for (int fm = 0; fm < 2; fm++)
      af[fm] = *(const bf16x8*)&lds_a[(wrow + fm * 16 + ln15) * 40 + kq8];
#pragma unroll
    for (int fn = 0; fn < 4; fn++) {
      bf16x8 bv = *(const bf16x8*)&lds_b[(wcol + fn * 16 + ln15) * 40 + kq8];
#pragma unroll
      for (int fm = 0; fm < 2; fm++)
        acc[fm][fn] = __builtin_amdgcn_mfma_f32_16x16x32_bf16(af[fm], bv, acc[fm][fn], 0, 0, 0);
    }
  }

  const int kq4 = ((tid & 63) >> 4) << 2;
#pragma unroll
  for (int fm = 0; fm < 2; fm++) {
#pragma unroll
    for (int r4 = 0; r4 < 4; r4++) {
      int mm = mtile * 128 + wrow + fm * 16 + kq4 + r4;
      if (mm < cnt) {
        int t; float wgt;
        if (shx) { t = t0 + mm; wgt = 1.f; }
        else { t = rows_tok[g0 + mm]; wgt = rows_wgt[g0 + mm]; }
        float* orow = out + (size_t)t * DD + n0;
#pragma unroll
        for (int fn = 0; fn < 4; fn++) {
          int nc = wcol + fn * 16 + ln15;
          float v = wgt * (acc[fm][fn][r4] + bf2[(size_t)z * DD + n0 + nc]);
          atomicAdd(&orow[nc], v);
        }
      }
    }
  }
}

extern "C" void kernel_launch(void* const* d_in, const int* in_sizes, int n_in,
                              void* d_out, int out_size, void* d_ws, size_t ws_size,
                              hipStream_t stream) {
  const void* x   = d_in[0];
  const void* gw  = d_in[1];
  const void* gb  = d_in[2];
  const void* w1  = d_in[3];
  const void* b1  = d_in[4];
  const void* w3  = d_in[5];
  const void* b3  = d_in[6];
  const void* w2  = d_in[7];
  const void* b2  = d_in[8];
  const void* sw1 = d_in[9];
  const void* sb1 = d_in[10];
  const void* sw3 = d_in[11];
  const void* sb3 = d_in[12];
  const void* sw2 = d_in[13];
  const void* sb2 = d_in[14];

  const int T = in_sizes[0] / DD;  // 4096
  (void)n_in; (void)out_size;

  const size_t WMAT = (size_t)(NE + 1) * HH * DD;  // elements per transposed array

  auto need = [&](int S) -> size_t {
    int TS = T / S;
    size_t o = 0;
    auto pad = [&](size_t b) { o = (o + b + 255) & ~(size_t)255; };
    pad(256);                                 // dflag
    pad(32 * sizeof(int));                    // meta
    pad((size_t)T * 2 * sizeof(int));         // tok_eidx
    pad((size_t)T * 2 * sizeof(float));       // tok_w
    pad((size_t)T * DD * 2);                  // xb
    pad(WMAT * 2);                            // wt1
    pad(WMAT * 2);                            // wt3
    pad(WMAT * 2);                            // wt2
    pad((size_t)(NE + 1) * HH * sizeof(float));  // bf1
    pad((size_t)(NE + 1) * HH * sizeof(float));  // bf3
    pad((size_t)(NE + 1) * DD * sizeof(float));  // bf2
    pad((size_t)TS * 2 * sizeof(int));        // rows_tok
    pad((size_t)TS * 2 * sizeof(float));      // rows_wgt
    pad((size_t)TS * 2 * HH * 2);             // h_buf
    pad((size_t)TS * HH * 2);                 // sh_buf
    return o;
  };
  int S = 32;
  {
    const int cand[6] = {1, 2, 4, 8, 16, 32};
    for (int ci = 0; ci < 6; ci++) {
      if (need(cand[ci]) <= ws_size) { S = cand[ci]; break; }
    }
  }
  const int TS = T / S;
  const int mt = TS / 128;

  char* w = (char*)d_ws;
  size_t off = 0;
  auto take = [&](size_t bytes) {
    char* p = w + off;
    off = (off + bytes + 255) & ~(size_t)255;
    return p;
  };
  int*   dflag    = (int*)  take(256);
  int*   meta     = (int*)  take(32 * sizeof(int));
  int*   tok_eidx = (int*)  take((size_t)T * 2 * sizeof(int));
  float* tok_w    = (float*)take((size_t)T * 2 * sizeof(float));
  unsigned short* xb  = (unsigned short*)take((size_t)T * DD * 2);
  unsigned short* wt1 = (unsigned short*)take(WMAT * 2);
  unsigned short* wt3 = (unsigned short*)take(WMAT * 2);
  unsigned short* wt2 = (unsigned short*)take(WMAT * 2);
  float* bf1 = (float*)take((size_t)(NE + 1) * HH * sizeof(float));
  float* bf3 = (float*)take((size_t)(NE + 1) * HH * sizeof(float));
  float* bf2 = (float*)take((size_t)(NE + 1) * DD * sizeof(float));
  int*   rows_tok = (int*)  take((size_t)TS * 2 * sizeof(int));
  float* rows_wgt = (float*)take((size_t)TS * 2 * sizeof(float));
  unsigned short* h_buf  = (unsigned short*)take((size_t)TS * 2 * HH * 2);
  unsigned short* sh_buf = (unsigned short*)take((size_t)TS * HH * 2);

  sniff_kernel<<<1, 256, 0, stream>>>((const unsigned short*)x, dflag);

  // pre-pass: bf16-ify everything, transpose weights to [N][K]
  cvtx_kernel<<<2048, 256, 0, stream>>>(x, dflag, xb, T * DD / 8);
  trans_kernel<<<dim3(HH / 32, DD / 32, NE + 1), 256, 0, stream>>>(w1, sw1, dflag, wt1, DD, HH);
  trans_kernel<<<dim3(HH / 32, DD / 32, NE + 1), 256, 0, stream>>>(w3, sw3, dflag, wt3, DD, HH);
  trans_kernel<<<dim3(DD / 32, HH / 32, NE + 1), 256, 0, stream>>>(w2, sw2, dflag, wt2, HH, DD);
  {
    int nb = (2 * (NE + 1) * HH + (NE + 1) * DD + 255) / 256;
    cvtb_kernel<<<nb, 256, 0, stream>>>(b1, b3, b2, sb1, sb3, sb2, dflag, bf1, bf3, bf2);
  }

  gate_kernel<<<(T + 3) / 4, 256, 0, stream>>>(x, gw, gb, dflag, tok_eidx, tok_w, T);
  zero_kernel<<<1024, 256, 0, stream>>>((float4*)d_out, T * DD / 4);

  for (int s = 0; s < S; s++) {
    const int t0 = s * TS;
    prep_kernel<<<1, 1024, 0, stream>>>(tok_eidx, tok_w, meta, rows_tok, rows_wgt, t0, TS);
    ffn_up_kernel<<<dim3(HH / 128, mt, NE + 1), 512, 0, stream>>>(
        xb, wt1, wt3, bf1, bf3, meta, rows_tok, h_buf, sh_buf, t0, TS);
    ffn_down_kernel<<<dim3(DD / 128, mt, NE + 1), 512, 0, stream>>>(
        h_buf, sh_buf, wt2, bf2, meta, rows_tok, rows_wgt, (float*)d_out, t0, TS);
  }
}

// Round 3
// 438.343 us; speedup vs baseline: 1.5041x; 1.1461x over previous
//
#include <hip/hip_runtime.h>
#include <math.h>

#define DD 1024   // hidden dim
#define HH 1408   // moe inter dim
#define NE 8      // experts

typedef __attribute__((ext_vector_type(8))) __bf16 bf16x8;
typedef __attribute__((ext_vector_type(4))) float f32x4;

__device__ __forceinline__ float bf2f(unsigned short u) {
  union { unsigned int i; float f; } v; v.i = ((unsigned int)u) << 16; return v.f;
}
__device__ __forceinline__ unsigned short f2bf(float f) {
  union { float f; unsigned int i; } v; v.f = f;
  unsigned int r = v.i + 0x7FFFu + ((v.i >> 16) & 1u);  // RNE
  return (unsigned short)(r >> 16);
}
__device__ __forceinline__ float tof(float f) { return f; }
__device__ __forceinline__ float tof(unsigned short u) { return bf2f(u); }

// pack bf16(a) | bf16(b)<<16 in ONE instruction (RNE, gfx950)
__device__ __forceinline__ void cvt2(float a, float b, unsigned int* o) {
  asm("v_cvt_pk_bf16_f32 %0, %1, %2" : "=v"(*o) : "v"(a), "v"(b));
}

__device__ __forceinline__ void ld8cvt(const float* p, unsigned int* o) {
  float4 a = *(const float4*)p;
  float4 b = *(const float4*)(p + 4);
  cvt2(a.x, a.y, o + 0); cvt2(a.z, a.w, o + 1);
  cvt2(b.x, b.y, o + 2); cvt2(b.z, b.w, o + 3);
}

// async global->LDS, 16 bytes per lane; LDS dest must be wave-uniform base
typedef unsigned int __attribute__((address_space(1))) gu32;
typedef unsigned int __attribute__((address_space(3))) lu32;
__device__ __forceinline__ void gl16(const unsigned short* g, unsigned short* l) {
  __builtin_amdgcn_global_load_lds((const gu32*)g, (lu32*)l, 16, 0, 0);
}

// ---------------- sniff input dtype: 1 = fp32, 0 = bf16 ----------------
__global__ void sniff_kernel(const unsigned short* __restrict__ xw,
                             int* __restrict__ dflag) {
  __shared__ int cnt;
  if (threadIdx.x == 0) cnt = 0;
  __syncthreads();
  unsigned short v = xw[threadIdx.x];
  int e = (v >> 7) & 0xFF;
  if (e >= 100 && e <= 140) atomicAdd(&cnt, 1);
  __syncthreads();
  if (threadIdx.x == 0) dflag[0] = (cnt < 230) ? 1 : 0;
}

// ---------------- convert x -> bf16 ----------------
__global__ void cvtx_kernel(const void* __restrict__ x,
                            const int* __restrict__ dflag,
                            unsigned short* __restrict__ xb, int n8) {
  int i = blockIdx.x * blockDim.x + threadIdx.x;
  int st = gridDim.x * blockDim.x;
  if (dflag[0]) {
    const float* xs = (const float*)x;
    for (; i < n8; i += st) {
      unsigned int o[4];
      ld8cvt(xs + (size_t)i * 8, o);
      *(uint4*)(xb + (size_t)i * 8) = *(uint4*)o;
    }
  } else {
    const uint4* xs = (const uint4*)x;
    for (; i < n8; i += st) *(uint4*)(xb + (size_t)i * 8) = xs[i];
  }
}

// ---------------- transpose+convert weights: [mat][R][C] -> [mat][C][R] bf16 ----
__global__ void trans_kernel(const void* __restrict__ wmain,
                             const void* __restrict__ wsh,
                             const int* __restrict__ dflag,
                             unsigned short* __restrict__ out, int R, int C) {
  __shared__ float tile[32][33];
  const int mat = blockIdx.z;
  const int r0 = blockIdx.y << 5, c0 = blockIdx.x << 5;
  const int t = threadIdx.x;                 // 256 threads
  const int lr = t >> 3, lc = (t & 7) << 2;
  const size_t mbase = (size_t)mat * R * C;
  if (dflag[0]) {
    const float* src = (mat < NE) ? ((const float*)wmain + mbase) : (const float*)wsh;
    float4 v = *(const float4*)(src + (size_t)(r0 + lr) * C + c0 + lc);
    tile[lr][lc] = v.x; tile[lr][lc + 1] = v.y;
    tile[lr][lc + 2] = v.z; tile[lr][lc + 3] = v.w;
  } else {
    const unsigned short* src = (mat < NE) ? ((const unsigned short*)wmain + mbase)
                                           : (const unsigned short*)wsh;
    ushort4 v = *(const ushort4*)(src + (size_t)(r0 + lr) * C + c0 + lc);
    tile[lr][lc] = bf2f(v.x); tile[lr][lc + 1] = bf2f(v.y);
    tile[lr][lc + 2] = bf2f(v.z); tile[lr][lc + 3] = bf2f(v.w);
  }
  __syncthreads();
  const int oc = t >> 3;
  const int orr = (t & 7) << 2;
  unsigned int p0, p1;
  cvt2(tile[orr][oc], tile[orr + 1][oc], &p0);
  cvt2(tile[orr + 2][oc], tile[orr + 3][oc], &p1);
  uint2 pk; pk.x = p0; pk.y = p1;
  *(uint2*)(out + mbase + (size_t)(c0 + oc) * R + r0 + orr) = pk;
}

// ---------------- biases -> f32, [NE+1] stacked (slot NE = shared) ----------
__global__ void cvtb_kernel(const void* b1, const void* b3, const void* b2,
                            const void* sb1, const void* sb3, const void* sb2,
                            const int* __restrict__ dflag,
                            float* __restrict__ bf1, float* __restrict__ bf3,
                            float* __restrict__ bf2o) {
  int i = blockIdx.x * blockDim.x + threadIdx.x;
  const int nh = (NE + 1) * HH, nd = (NE + 1) * DD;
  const bool f32 = dflag[0] != 0;
  auto get = [&](const void* pm, const void* ps, int idx, int per) -> float {
    int mat = idx / per, j = idx - mat * per;
    if (f32) return (mat < NE) ? ((const float*)pm)[(size_t)mat * per + j]
                               : ((const float*)ps)[j];
    return bf2f((mat < NE) ? ((const unsigned short*)pm)[(size_t)mat * per + j]
                           : ((const unsigned short*)ps)[j]);
  };
  if (i < nh) bf1[i] = get(b1, sb1, i, HH);
  else if (i < 2 * nh) bf3[i - nh] = get(b3, sb3, i - nh, HH);
  else if (i < 2 * nh + nd) bf2o[i - 2 * nh] = get(b2, sb2, i - 2 * nh, DD);
}

// ---------------- gate: one wave per token ----------------
template <class T>
__device__ void gate_body(const T* __restrict__ x,
                          const T* __restrict__ gw,
                          const T* __restrict__ gb,
                          int* __restrict__ tok_eidx,
                          float* __restrict__ tok_w, int T_) {
  int t = (int)((blockIdx.x * blockDim.x + threadIdx.x) >> 6);
  int lane = threadIdx.x & 63;
  if (t >= T_) return;
  const T* xr = x + (size_t)t * DD;
  float acc[NE];
#pragma unroll
  for (int e = 0; e < NE; e++) acc[e] = 0.f;
  for (int i = lane; i < DD; i += 64) {
    float xv = tof(xr[i]);
#pragma unroll
    for (int e = 0; e < NE; e++) acc[e] += xv * tof(gw[e * DD + i]);
  }
#pragma unroll
  for (int off = 32; off > 0; off >>= 1) {
#pragma unroll
    for (int e = 0; e < NE; e++) acc[e] += __shfl_xor(acc[e], off);
  }
  if (lane == 0) {
    float mx = acc[0];
#pragma unroll
    for (int e = 1; e < NE; e++) mx = fmaxf(mx, acc[e]);
    float s = 0.f, sc[NE], bi[NE];
#pragma unroll
    for (int e = 0; e < NE; e++) { sc[e] = expf(acc[e] - mx); s += sc[e]; }
    float inv = 1.f / s;
#pragma unroll
    for (int e = 0; e < NE; e++) { sc[e] *= inv; bi[e] = sc[e] + tof(gb[e]); }
    int i1 = 0;
#pragma unroll
    for (int e = 1; e < NE; e++) if (bi[e] > bi[i1]) i1 = e;
    int i2 = (i1 == 0) ? 1 : 0;
#pragma unroll
    for (int e = 0; e < NE; e++) if (e != i1 && bi[e] > bi[i2]) i2 = e;
    tok_eidx[t * 2] = i1; tok_eidx[t * 2 + 1] = i2;
    tok_w[t * 2] = sc[i1]; tok_w[t * 2 + 1] = sc[i2];
  }
}

__global__ void gate_kernel(const void* x, const void* gw, const void* gb,
                            const int* __restrict__ dflag,
                            int* tok_eidx, float* tok_w, int T_) {
  if (dflag[0])
    gate_body<float>((const float*)x, (const float*)gw, (const float*)gb,
                     tok_eidx, tok_w, T_);
  else
    gate_body<unsigned short>((const unsigned short*)x, (const unsigned short*)gw,
                              (const unsigned short*)gb, tok_eidx, tok_w, T_);
}

// ---------------- fused count + scan + scatter (single block) ----------------
__global__ void prep_kernel(const int* __restrict__ tok_eidx,
                            const float* __restrict__ tok_w,
                            int* __restrict__ meta,
                            int* __restrict__ rows_tok,
                            float* __restrict__ rows_wgt,
                            int t0, int TS) {
  __shared__ int cnt[NE];
  __shared__ int off[NE];
  const int tid = threadIdx.x;
  if (tid < NE) cnt[tid] = 0;
  __syncthreads();
  const int n2 = TS * 2;
  const int* te = tok_eidx + (size_t)t0 * 2;
  const float* tw = tok_w + (size_t)t0 * 2;
  for (int i = tid; i < n2; i += (int)blockDim.x) atomicAdd(&cnt[te[i]], 1);
  __syncthreads();
  if (tid == 0) {
    int s = 0;
#pragma unroll
    for (int e = 0; e < NE; e++) { off[e] = s; meta[16 + e] = s; s += cnt[e]; }
    meta[16 + NE] = s;
  }
  __syncthreads();
  for (int i = tid; i < n2; i += (int)blockDim.x) {
    int pos = atomicAdd(&off[te[i]], 1);
    rows_tok[pos] = t0 + (i >> 1);
    rows_wgt[pos] = tw[i];
  }
}

// ---------------- zero fp32 output ----------------
__global__ void zero_kernel(float4* __restrict__ p, int n4) {
  int i = blockIdx.x * blockDim.x + threadIdx.x;
  int st = gridDim.x * blockDim.x;
  float4 z; z.x = z.y = z.z = z.w = 0.f;
  for (; i < n4; i += st) p[i] = z;
}

// ============ up-projection: M256 x N128, BK=64, XOR-swizzled LDS,
// ============ global_load_lds + 2-phase double buffer, 8 waves (4x2)
// LDS row = 128B (64 bf16). Logical slot s at row r lives at phys slot s^(r&7).
__global__ __launch_bounds__(512, 2)
void ffn_up_kernel(const unsigned short* __restrict__ xb,
                   const unsigned short* __restrict__ wt1,
                   const unsigned short* __restrict__ wt3,
                   const float* __restrict__ bf1, const float* __restrict__ bf3,
                   const int* __restrict__ meta,
                   const int* __restrict__ rows_tok,
                   unsigned short* __restrict__ h_buf,
                   unsigned short* __restrict__ sh_buf,
                   int t0, int TS) {
  const int z = blockIdx.z;
  const bool shx = (z == NE);
  int g0, cnt;
  unsigned short* ho;
  if (shx) { g0 = 0; cnt = TS; ho = sh_buf; }
  else {
    g0 = meta[16 + z]; cnt = meta[17 + z] - g0;
    ho = h_buf + (size_t)g0 * HH;
  }
  const int mtile = blockIdx.y;
  if (mtile * 256 >= cnt) return;
  const int n0 = blockIdx.x * 128;
  const unsigned short* wa = wt1 + (size_t)z * HH * DD;  // [HH][DD] bf16
  const unsigned short* wb = wt3 + (size_t)z * HH * DD;

  // per buffer: A 256x64 (16384) + B1 128x64 (8192) + B3 128x64 (8192) shorts
  __shared__ alignas(16) unsigned short lds[2 * 32768];

  const int tid = threadIdx.x;
  const int lane = tid & 63, wid = tid >> 6;
  const int rsub = wid * 8 + (lane >> 3);        // row within 64-row chunk
  const int sl8 = (((lane & 7) ^ (lane >> 3)) << 3);  // swizzled source col (elems)

  // A: 4 chunks of 64 rows (gathered token rows)
  size_t aoff[4];
#pragma unroll
  for (int c = 0; c < 4; c++) {
    int r = c * 64 + rsub;
    int m = mtile * 256 + r;
    int rr = (m < cnt) ? m : (cnt - 1);
    int srow = shx ? (t0 + rr) : rows_tok[g0 + rr];
    aoff[c] = (size_t)srow * DD + sl8;
  }
  // B: 2 chunks of 64 rows (weight rows n0+r)
  size_t boff[2];
#pragma unroll
  for (int c = 0; c < 2; c++)
    boff[c] = (size_t)(n0 + c * 64 + rsub) * DD + sl8;

  const int ln15 = lane & 15;
  const int lg = lane >> 4;           // 0..3
  const int wr = (wid >> 1) << 6;     // 0,64,128,192
  const int wc = (wid & 1) << 6;      // 0,64
  const int ldsw = wid * 512;         // wave's 1KB chunk base (elems = 512 shorts)

  f32x4 acc1[4][4], acc3[4][4];
#pragma unroll
  for (int a = 0; a < 4; a++)
#pragma unroll
    for (int b = 0; b < 4; b++) {
      acc1[a][b] = {0.f, 0.f, 0.f, 0.f};
      acc3[a][b] = {0.f, 0.f, 0.f, 0.f};
    }

  auto stage = [&](int buf, int k) {
    unsigned short* Lb = &lds[buf * 32768];
#pragma unroll
    for (int c = 0; c < 4; c++)
      gl16(xb + aoff[c] + k, Lb + c * 4096 + ldsw);
#pragma unroll
    for (int c = 0; c < 2; c++) {
      gl16(wa + boff[c] + k, Lb + 16384 + c * 4096 + ldsw);
      gl16(wb + boff[c] + k, Lb + 24576 + c * 4096 + ldsw);
    }
  };

  stage(0, 0);
  const int NT = DD / 64;  // 16
  for (int t = 0; t < NT; ++t) {
    asm volatile("s_waitcnt vmcnt(0)" ::: "memory");
    __syncthreads();
    if (t + 1 < NT) stage((t + 1) & 1, (t + 1) * 64);
    const unsigned short* Lb = &lds[(t & 1) * 32768];
#pragma unroll
    for (int ks = 0; ks < 2; ks++) {
      bf16x8 af[4];
#pragma unroll
      for (int fm = 0; fm < 4; fm++) {
        int R = wr + fm * 16 + ln15;
        af[fm] = *(const bf16x8*)&Lb[R * 64 + ((((ks << 2) | lg) ^ (R & 7)) << 3)];
      }
#pragma unroll
      for (int fn = 0; fn < 4; fn++) {
        int Rb = wc + fn * 16 + ln15;
        int o = Rb * 64 + ((((ks << 2) | lg) ^ (Rb & 7)) << 3);
        bf16x8 b1v = *(const bf16x8*)&Lb[16384 + o];
        bf16x8 b3v = *(const bf16x8*)&Lb[24576 + o];
#pragma unroll
        for (int fm = 0; fm < 4; fm++) {
          acc1[fm][fn] = __builtin_amdgcn_mfma_f32_16x16x32_bf16(af[fm], b1v, acc1[fm][fn], 0, 0, 0);
          acc3[fm][fn] = __builtin_amdgcn_mfma_f32_16x16x32_bf16(af[fm], b3v, acc3[fm][fn], 0, 0, 0);
        }
      }
    }
  }

  const int kq4 = lg << 2;
#pragma unroll
  for (int fm = 0; fm < 4; fm++) {
#pragma unroll
    for (int r = 0; r < 4; r++) {
      int m = mtile * 256 + wr + fm * 16 + kq4 + r;
      if (m < cnt) {
        unsigned short* orow = ho + (size_t)m * HH + n0;
#pragma unroll
        for (int fn = 0; fn < 4; fn++) {
          int nc = wc + fn * 16 + ln15;
          float g1 = acc1[fm][fn][r] + bf1[(size_t)z * HH + n0 + nc];
          float g3 = acc3[fm][fn][r] + bf3[(size_t)z * HH + n0 + nc];
          float u = g1 * g3;
          float hv = u * __builtin_amdgcn_rcpf(1.f + __expf(-u));  // silu(g1*g3)
          orow[nc] = f2bf(hv);
        }
      }
    }
  }
}

// ============ down-projection: M256 x N128, BK=64, same pipeline ============
__global__ __launch_bounds__(512, 2)
void ffn_down_kernel(const unsigned short* __restrict__ h_buf,
                     const unsigned short* __restrict__ sh_buf,
                     const unsigned short* __restrict__ wt2,
                     const float* __restrict__ bf2,
                     const int* __restrict__ meta,
                     const int* __restrict__ rows_tok,
                     const float* __restrict__ rows_wgt,
                     float* __restrict__ out, int t0, int TS) {
  const int z = blockIdx.z;
  const bool shx = (z == NE);
  int g0, cnt;
  const unsigned short* hb;
  if (shx) { g0 = 0; cnt = TS; hb = sh_buf; }
  else {
    g0 = meta[16 + z]; cnt = meta[17 + z] - g0;
    hb = h_buf + (size_t)g0 * HH;
  }
  const int mtile = blockIdx.y;
  if (mtile * 256 >= cnt) return;
  const int n0 = blockIdx.x * 128;
  const unsigned short* ws = wt2 + (size_t)z * DD * HH;  // [DD][HH] bf16

  // per buffer: A 256x64 (16384) + B 128x64 (8192) shorts
  __shared__ alignas(16) unsigned short lds[2 * 24576];

  const int tid = threadIdx.x;
  const int lane = tid & 63, wid = tid >> 6;
  const int rsub = wid * 8 + (lane >> 3);
  const int sl8 = (((lane & 7) ^ (lane >> 3)) << 3);

  size_t aoff[4];
#pragma unroll
  for (int c = 0; c < 4; c++) {
    int r = c * 64 + rsub;
    int m = mtile * 256 + r;
    int rr = (m < cnt) ? m : (cnt - 1);
    aoff[c] = (size_t)rr * HH + sl8;
  }
  size_t boff[2];
#pragma unroll
  for (int c = 0; c < 2; c++)
    boff[c] = (size_t)(n0 + c * 64 + rsub) * HH + sl8;

  const int ln15 = lane & 15;
  const int lg = lane >> 4;
  const int wr = (wid >> 1) << 6;
  const int wc = (wid & 1) << 6;
  const int ldsw = wid * 512;

  f32x4 acc[4][4];
#pragma unroll
  for (int a = 0; a < 4; a++)
#pragma unroll
    for (int b = 0; b < 4; b++) acc[a][b] = {0.f, 0.f, 0.f, 0.f};

  auto stage = [&](int buf, int k) {
    unsigned short* Lb = &lds[buf * 24576];
#pragma unroll
    for (int c = 0; c < 4; c++)
      gl16(hb + aoff[c] + k, Lb + c * 4096 + ldsw);
#pragma unroll
    for (int c = 0; c < 2; c++)
      gl16(ws + boff[c] + k, Lb + 16384 + c * 4096 + ldsw);
  };

  stage(0, 0);
  const int NT = HH / 64;  // 22
  for (int t = 0; t < NT; ++t) {
    asm volatile("s_waitcnt vmcnt(0)" ::: "memory");
    __syncthreads();
    if (t + 1 < NT) stage((t + 1) & 1, (t + 1) * 64);
    const unsigned short* Lb = &lds[(t & 1) * 24576];
#pragma unroll
    for (int ks = 0; ks < 2; ks++) {
      bf16x8 af[4];
#pragma unroll
      for (int fm = 0; fm < 4; fm++) {
        int R = wr + fm * 16 + ln15;
        af[fm] = *(const bf16x8*)&Lb[R * 64 + ((((ks << 2) | lg) ^ (R & 7)) << 3)];
      }
#pragma unroll
      for (int fn = 0; fn < 4; fn++) {
        int Rb = wc + fn * 16 + ln15;
        int o = Rb * 64 + ((((ks << 2) | lg) ^ (Rb & 7)) << 3);
        bf16x8 bv = *(const bf16x8*)&Lb[16384 + o];
#pragma unroll
        for (int fm = 0; fm < 4; fm++)
          acc[fm][fn] = __builtin_amdgcn_mfma_f32_16x16x32_bf16(af[fm], bv, acc[fm][fn], 0, 0, 0);
      }
    }
  }

  const int kq4 = lg << 2;
#pragma unroll
  for (int fm = 0; fm < 4; fm++) {
#pragma unroll
    for (int r4 = 0; r4 < 4; r4++) {
      int m = mtile * 256 + wr + fm * 16 + kq4 + r4;
      if (m < cnt) {
        int t; float wgt;
        if (shx) { t = t0 + m; wgt = 1.f; }
        else { t = rows_tok[g0 + m]; wgt = rows_wgt[g0 + m]; }
        float* orow = out + (size_t)t * DD + n0;
#pragma unroll
        for (int fn = 0; fn < 4; fn++) {
          int nc = wc + fn * 16 + ln15;
          float v = wgt * (acc[fm][fn][r4] + bf2[(size_t)z * DD + n0 + nc]);
          atomicAdd(&orow[nc], v);
        }
      }
    }
  }
}

extern "C" void kernel_launch(void* const* d_in, const int* in_sizes, int n_in,
                              void* d_out, int out_size, void* d_ws, size_t ws_size,
                              hipStream_t stream) {
  const void* x   = d_in[0];
  const void* gw  = d_in[1];
  const void* gb  = d_in[2];
  const void* w1  = d_in[3];
  const void* b1  = d_in[4];
  const void* w3  = d_in[5];
  const void* b3  = d_in[6];
  const void* w2  = d_in[7];
  const void* b2  = d_in[8];
  const void* sw1 = d_in[9];
  const void* sb1 = d_in[10];
  const void* sw3 = d_in[11];
  const void* sb3 = d_in[12];
  const void* sw2 = d_in[13];
  const void* sb2 = d_in[14];

  const int T = in_sizes[0] / DD;  // 4096
  (void)n_in; (void)out_size;

  const size_t WMAT = (size_t)(NE + 1) * HH * DD;

  auto need = [&](int S) -> size_t {
    int TS = T / S;
    size_t o = 0;
    auto pad = [&](size_t b) { o = (o + b + 255) & ~(size_t)255; };
    pad(256);
    pad(32 * sizeof(int));
    pad((size_t)T * 2 * sizeof(int));
    pad((size_t)T * 2 * sizeof(float));
    pad((size_t)T * DD * 2);
    pad(WMAT * 2);
    pad(WMAT * 2);
    pad(WMAT * 2);
    pad((size_t)(NE + 1) * HH * sizeof(float));
    pad((size_t)(NE + 1) * HH * sizeof(float));
    pad((size_t)(NE + 1) * DD * sizeof(float));
    pad((size_t)TS * 2 * sizeof(int));
    pad((size_t)TS * 2 * sizeof(float));
    pad((size_t)TS * 2 * HH * 2);
    pad((size_t)TS * HH * 2);
    return o;
  };
  int S = 32;
  {
    const int cand[6] = {1, 2, 4, 8, 16, 32};
    for (int ci = 0; ci < 6; ci++) {
      if (need(cand[ci]) <= ws_size) { S = cand[ci]; break; }
    }
  }
  const int TS = T / S;
  const int my = (TS + 255) / 256;

  char* w = (char*)d_ws;
  size_t off = 0;
  auto take = [&](size_t bytes) {
    char* p = w + off;
    off = (off + bytes + 255) & ~(size_t)255;
    return p;
  };
  int*   dflag    = (int*)  take(256);
  int*   meta     = (int*)  take(32 * sizeof(int));
  int*   tok_eidx = (int*)  take((size_t)T * 2 * sizeof(int));
  float* tok_w    = (float*)take((size_t)T * 2 * sizeof(float));
  unsigned short* xb  = (unsigned short*)take((size_t)T * DD * 2);
  unsigned short* wt1 = (unsigned short*)take(WMAT * 2);
  unsigned short* wt3 = (unsigned short*)take(WMAT * 2);
  unsigned short* wt2 = (unsigned short*)take(WMAT * 2);
  float* bf1 = (float*)take((size_t)(NE + 1) * HH * sizeof(float));
  float* bf3 = (float*)take((size_t)(NE + 1) * HH * sizeof(float));
  float* bf2 = (float*)take((size_t)(NE + 1) * DD * sizeof(float));
  int*   rows_tok = (int*)  take((size_t)TS * 2 * sizeof(int));
  float* rows_wgt = (float*)take((size_t)TS * 2 * sizeof(float));
  unsigned short* h_buf  = (unsigned short*)take((size_t)TS * 2 * HH * 2);
  unsigned short* sh_buf = (unsigned short*)take((size_t)TS * HH * 2);

  sniff_kernel<<<1, 256, 0, stream>>>((const unsigned short*)x, dflag);

  cvtx_kernel<<<2048, 256, 0, stream>>>(x, dflag, xb, T * DD / 8);
  trans_kernel<<<dim3(HH / 32, DD / 32, NE + 1), 256, 0, stream>>>(w1, sw1, dflag, wt1, DD, HH);
  trans_kernel<<<dim3(HH / 32, DD / 32, NE + 1), 256, 0, stream>>>(w3, sw3, dflag, wt3, DD, HH);
  trans_kernel<<<dim3(DD / 32, HH / 32, NE + 1), 256, 0, stream>>>(w2, sw2, dflag, wt2, HH, DD);
  {
    int nb = (2 * (NE + 1) * HH + (NE + 1) * DD + 255) / 256;
    cvtb_kernel<<<nb, 256, 0, stream>>>(b1, b3, b2, sb1, sb3, sb2, dflag, bf1, bf3, bf2);
  }

  gate_kernel<<<(T + 3) / 4, 256, 0, stream>>>(x, gw, gb, dflag, tok_eidx, tok_w, T);
  zero_kernel<<<1024, 256, 0, stream>>>((float4*)d_out, T * DD / 4);

  for (int s = 0; s < S; s++) {
    const int t0 = s * TS;
    prep_kernel<<<1, 1024, 0, stream>>>(tok_eidx, tok_w, meta, rows_tok, rows_wgt, t0, TS);
    ffn_up_kernel<<<dim3(HH / 128, my, NE + 1), 512, 0, stream>>>(
        xb, wt1, wt3, bf1, bf3, meta, rows_tok, h_buf, sh_buf, t0, TS);
    ffn_down_kernel<<<dim3(DD / 128, my, NE + 1), 512, 0, stream>>>(
        h_buf, sh_buf, wt2, bf2, meta, rows_tok, rows_wgt, (float*)d_out, t0, TS);
  }
}